// Round 1
// baseline (1300.765 us; speedup 1.0000x reference)
//
#include <hip/hip_runtime.h>
#include <stdint.h>

typedef unsigned short u16;
typedef unsigned int u32;
typedef short bf16x8 __attribute__((ext_vector_type(8)));
typedef float f32x4 __attribute__((ext_vector_type(4)));

#define E_ 8
#define H_ 2048
#define F_ 4096
#define T_ 16384
#define TE_ 2048  // tokens per expert

// ---------- helpers ----------

__device__ __forceinline__ u16 f2bf(float f) {
  u32 u = __builtin_bit_cast(u32, f);
  u32 r = (u + 0x7FFFu + ((u >> 16) & 1u)) >> 16;  // RNE
  return (u16)r;
}

__device__ __forceinline__ void gload_lds16(const u16* g, u16* l) {
  __builtin_amdgcn_global_load_lds(
      (__attribute__((address_space(1))) void*)g,
      (__attribute__((address_space(3))) void*)l, 16, 0, 0);
}

// D = A(16x32) * B(32x16) + D, bf16 in / f32 acc. Inline asm avoids any
// builtin operand-type ambiguity; gfx950 unified VGPR file allows v[] C/D.
__device__ __forceinline__ void mfma_b(f32x4& acc, bf16x8 a, bf16x8 b) {
  asm volatile("v_mfma_f32_16x16x32_bf16 %0, %1, %2, %0"
               : "+v"(acc)
               : "v"(a), "v"(b));
}

// ---------- fp32 -> bf16 convert (vectorized, grid-stride) ----------

__global__ __launch_bounds__(256) void cvt_kernel(const float* __restrict__ src,
                                                  u16* __restrict__ dst,
                                                  long n4) {
  long i = (long)blockIdx.x * blockDim.x + threadIdx.x;
  long stride = (long)gridDim.x * blockDim.x;
  const float4* s4 = (const float4*)src;
  uint2* d4 = (uint2*)dst;
  for (; i < n4; i += stride) {
    float4 v = s4[i];
    uint2 o;
    o.x = (u32)f2bf(v.x) | ((u32)f2bf(v.y) << 16);
    o.y = (u32)f2bf(v.z) | ((u32)f2bf(v.w) << 16);
    d4[i] = o;
  }
}

// ---------- GEMM1 fused: hidden = silu(x @ Wg^T) * (x @ Wu^T) ----------
// Block computes a 128x64 hidden tile. 4 waves in 2x2; wave tile 64x32.
// K = H_ (2048). A = x_e [TE_][H_], W = wgu_e [2F_][H_], out bf16 [TE_][F_].

__global__ __launch_bounds__(256) void gemm1_silu(const u16* __restrict__ Xb,
                                                  const u16* __restrict__ Wgu,
                                                  u16* __restrict__ Hid,
                                                  long sX, long sW, long sH) {
  const int z = blockIdx.z;
  Xb += (long)z * sX;
  Wgu += (long)z * sW;
  Hid += (long)z * sH;

  const int bx = blockIdx.x;  // F tile (64 cols)
  const int by = blockIdx.y;  // row tile (128 rows)
  const int tid = threadIdx.x;
  const int w = tid >> 6;
  const int lane = tid & 63;
  const int wr = w >> 1, wc = w & 1;

  __shared__ __attribute__((aligned(16))) u16 As[128 * 32];
  __shared__ __attribute__((aligned(16))) u16 Bg[64 * 32];
  __shared__ __attribute__((aligned(16))) u16 Bu[64 * 32];

  const int rowBase = by * 128;
  const int colBase = bx * 64;

  // staging lane pattern: 16 rows per 1KiB chunk, 4 lanes (16B each) per row
  const int sr = lane >> 2;        // row within chunk
  const int sc = (lane & 3) * 8;   // elem col within 32-elem k-slab

  const u16* gA = Xb + (size_t)(rowBase + w * 32 + sr) * H_ + sc;
  const int bRow0 = (w & 1) * 32;
  const size_t wRow = (w < 2) ? (size_t)(colBase + bRow0 + sr) * H_
                              : (size_t)(F_ + colBase + bRow0 + sr) * H_;
  const u16* gB = Wgu + wRow + sc;
  u16* lB = (w < 2) ? (u16*)Bg : (u16*)Bu;
  const int lBoff = bRow0 * 32;

  f32x4 zero4 = {0.f, 0.f, 0.f, 0.f};
  f32x4 accG[4][2], accU[4][2];
#pragma unroll
  for (int m = 0; m < 4; ++m)
#pragma unroll
    for (int n = 0; n < 2; ++n) {
      accG[m][n] = zero4;
      accU[m][n] = zero4;
    }

  const int fr = lane & 15;
  const int fk = (lane >> 4) * 8;

  for (int k0 = 0; k0 < H_; k0 += 32) {
    // stage A (8 KiB) + B gate/up (4+4 KiB): 4 x 1KiB chunks per wave
    gload_lds16(gA + k0, &As[(w * 32) * 32]);
    gload_lds16(gA + k0 + 16 * H_, &As[(w * 32 + 16) * 32]);
    gload_lds16(gB + k0, &lB[lBoff]);
    gload_lds16(gB + k0 + 16 * H_, &lB[lBoff + 16 * 32]);
    __syncthreads();

    bf16x8 a[4], bg[2], bu[2];
#pragma unroll
    for (int m = 0; m < 4; ++m)
      a[m] = *(const bf16x8*)&As[(wr * 64 + m * 16 + fr) * 32 + fk];
#pragma unroll
    for (int n = 0; n < 2; ++n) {
      bg[n] = *(const bf16x8*)&Bg[(wc * 32 + n * 16 + fr) * 32 + fk];
      bu[n] = *(const bf16x8*)&Bu[(wc * 32 + n * 16 + fr) * 32 + fk];
    }
#pragma unroll
    for (int m = 0; m < 4; ++m)
#pragma unroll
      for (int n = 0; n < 2; ++n) {
        mfma_b(accG[m][n], a[m], bg[n]);
        mfma_b(accU[m][n], a[m], bu[n]);
      }
    __syncthreads();
  }

  // epilogue: silu(g)*u -> bf16
  const int cr = (lane >> 4) * 4;
  const int cc = lane & 15;
#pragma unroll
  for (int m = 0; m < 4; ++m)
#pragma unroll
    for (int n = 0; n < 2; ++n)
#pragma unroll
      for (int j = 0; j < 4; ++j) {
        int row = rowBase + wr * 64 + m * 16 + cr + j;
        int col = colBase + wc * 32 + n * 16 + cc;
        float g = accG[m][n][j];
        float u = accU[m][n][j];
        float h = (g / (1.f + __expf(-g))) * u;
        Hid[(size_t)row * F_ + col] = f2bf(h);
      }
}

// ---------- GEMM2: out = hidden @ w_down^T (fp32 out) ----------
// 128x128 tile, 4 waves 2x2, wave tile 64x64. K = F_ (4096).

__global__ __launch_bounds__(256) void gemm2_down(const u16* __restrict__ Hd,
                                                  const u16* __restrict__ Wd,
                                                  float* __restrict__ Out,
                                                  long sH, long sW, long sO) {
  const int z = blockIdx.z;
  Hd += (long)z * sH;
  Wd += (long)z * sW;
  Out += (long)z * sO;

  const int bx = blockIdx.x;  // H tile (128 cols)
  const int by = blockIdx.y;  // row tile (128 rows)
  const int tid = threadIdx.x;
  const int w = tid >> 6;
  const int lane = tid & 63;
  const int wr = w >> 1, wc = w & 1;

  __shared__ __attribute__((aligned(16))) u16 As[128 * 32];
  __shared__ __attribute__((aligned(16))) u16 Bs[128 * 32];

  const int rowBase = by * 128;
  const int colBase = bx * 128;

  const int sr = lane >> 2;
  const int sc = (lane & 3) * 8;

  const u16* gA = Hd + (size_t)(rowBase + w * 32 + sr) * F_ + sc;
  const u16* gB = Wd + (size_t)(colBase + w * 32 + sr) * F_ + sc;

  f32x4 zero4 = {0.f, 0.f, 0.f, 0.f};
  f32x4 acc[4][4];
#pragma unroll
  for (int m = 0; m < 4; ++m)
#pragma unroll
    for (int n = 0; n < 4; ++n) acc[m][n] = zero4;

  const int fr = lane & 15;
  const int fk = (lane >> 4) * 8;

  for (int k0 = 0; k0 < F_; k0 += 32) {
    gload_lds16(gA + k0, &As[(w * 32) * 32]);
    gload_lds16(gA + k0 + 16 * F_, &As[(w * 32 + 16) * 32]);
    gload_lds16(gB + k0, &Bs[(w * 32) * 32]);
    gload_lds16(gB + k0 + 16 * F_, &Bs[(w * 32 + 16) * 32]);
    __syncthreads();

    bf16x8 a[4], b[4];
#pragma unroll
    for (int m = 0; m < 4; ++m)
      a[m] = *(const bf16x8*)&As[(wr * 64 + m * 16 + fr) * 32 + fk];
#pragma unroll
    for (int n = 0; n < 4; ++n)
      b[n] = *(const bf16x8*)&Bs[(wc * 64 + n * 16 + fr) * 32 + fk];
#pragma unroll
    for (int m = 0; m < 4; ++m)
#pragma unroll
      for (int n = 0; n < 4; ++n) mfma_b(acc[m][n], a[m], b[n]);
    __syncthreads();
  }

  const int cr = (lane >> 4) * 4;
  const int cc = lane & 15;
#pragma unroll
  for (int m = 0; m < 4; ++m)
#pragma unroll
    for (int n = 0; n < 4; ++n)
#pragma unroll
      for (int j = 0; j < 4; ++j) {
        int row = rowBase + wr * 64 + m * 16 + cr + j;
        int col = colBase + wc * 64 + n * 16 + cc;
        Out[(size_t)row * H_ + col] = acc[m][n][j];
      }
}

// ---------- host ----------

extern "C" void kernel_launch(void* const* d_in, const int* in_sizes, int n_in,
                              void* d_out, int out_size, void* d_ws,
                              size_t ws_size, hipStream_t stream) {
  (void)in_sizes;
  (void)n_in;
  (void)out_size;
  const float* x = (const float*)d_in[0];
  const float* wgu = (const float*)d_in[1];
  const float* wdn = (const float*)d_in[2];
  // d_in[3] tokens_per_expert: fixed equal split, unused
  float* out = (float*)d_out;
  u16* ws = (u16*)d_ws;

  const size_t xbN = (size_t)T_ * H_;          // 33,554,432
  const size_t wguN = (size_t)E_ * 2 * F_ * H_;  // 134,217,728
  const size_t wdnN = (size_t)E_ * H_ * F_;      // 67,108,864
  const size_t hidN = (size_t)T_ * F_;           // 67,108,864
  const size_t fullBytes = (xbN + wguN + wdnN + hidN) * 2;  // 576 MiB

  dim3 blk(256);

  if (ws_size >= fullBytes) {
    // full-batch path: convert everything once, batched GEMMs over experts
    u16* xb = ws;
    u16* wgub = xb + xbN;
    u16* wdnb = wgub + wguN;
    u16* hid = wdnb + wdnN;
    cvt_kernel<<<2048, blk, 0, stream>>>(x, xb, (long)(xbN / 4));
    cvt_kernel<<<4096, blk, 0, stream>>>(wgu, wgub, (long)(wguN / 4));
    cvt_kernel<<<4096, blk, 0, stream>>>(wdn, wdnb, (long)(wdnN / 4));
    gemm1_silu<<<dim3(F_ / 64, TE_ / 128, E_), blk, 0, stream>>>(
        xb, wgub, hid, (long)TE_ * H_, (long)2 * F_ * H_, (long)TE_ * F_);
    gemm2_down<<<dim3(H_ / 128, TE_ / 128, E_), blk, 0, stream>>>(
        hid, wdnb, out, (long)TE_ * F_, (long)H_ * F_, (long)TE_ * H_);
  } else {
    // per-expert path: 72 MiB of ws reused across experts (stream-serialized)
    u16* xb = ws;                          // TE_*H_
    u16* wgub = xb + (size_t)TE_ * H_;     // 2F_*H_
    u16* wdnb = wgub + (size_t)2 * F_ * H_;  // H_*F_
    u16* hid = wdnb + (size_t)H_ * F_;       // TE_*F_
    for (int e = 0; e < E_; ++e) {
      cvt_kernel<<<1024, blk, 0, stream>>>(x + (size_t)e * TE_ * H_, xb,
                                           (long)((size_t)TE_ * H_ / 4));
      cvt_kernel<<<2048, blk, 0, stream>>>(wgu + (size_t)e * 2 * F_ * H_, wgub,
                                           (long)((size_t)2 * F_ * H_ / 4));
      cvt_kernel<<<2048, blk, 0, stream>>>(wdn + (size_t)e * H_ * F_, wdnb,
                                           (long)((size_t)H_ * F_ / 4));
      gemm1_silu<<<dim3(F_ / 64, TE_ / 128, 1), blk, 0, stream>>>(xb, wgub, hid,
                                                                  0, 0, 0);
      gemm2_down<<<dim3(H_ / 128, TE_ / 128, 1), blk, 0, stream>>>(
          hid, wdnb, out + (size_t)e * TE_ * H_, 0, 0, 0);
    }
  }
}

// Round 2
// 1126.280 us; speedup vs baseline: 1.1549x; 1.1549x over previous
//
#include <hip/hip_runtime.h>
#include <stdint.h>

typedef unsigned short u16;
typedef unsigned int u32;
typedef short bf16x8 __attribute__((ext_vector_type(8)));
typedef float f32x4 __attribute__((ext_vector_type(4)));

#define E_ 8
#define H_ 2048
#define F_ 4096
#define T_ 16384
#define TE_ 2048

#define WAITV(n) asm volatile("s_waitcnt vmcnt(" #n ")" ::: "memory")
#define FENCE asm volatile("" ::: "memory")
#define BAR __builtin_amdgcn_s_barrier()

__device__ __forceinline__ u16 f2bf(float f) {
  u32 u = __builtin_bit_cast(u32, f);
  u32 r = (u + 0x7FFFu + ((u >> 16) & 1u)) >> 16;  // RNE
  return (u16)r;
}

__device__ __forceinline__ void gload16(const u16* g, u16* l) {
  __builtin_amdgcn_global_load_lds(
      (__attribute__((address_space(1))) void*)g,
      (__attribute__((address_space(3))) void*)l, 16, 0, 0);
}

__device__ __forceinline__ void mfma_b(f32x4& acc, bf16x8 a, bf16x8 b) {
  asm volatile("v_mfma_f32_16x16x32_bf16 %0, %1, %2, %0"
               : "+v"(acc)
               : "v"(a), "v"(b));
}

// ---------- fp32 -> bf16 convert ----------

__global__ __launch_bounds__(256) void cvt_kernel(const float* __restrict__ src,
                                                  u16* __restrict__ dst,
                                                  long n4) {
  long i = (long)blockIdx.x * blockDim.x + threadIdx.x;
  long stride = (long)gridDim.x * blockDim.x;
  const float4* s4 = (const float4*)src;
  uint2* d4 = (uint2*)dst;
  for (; i < n4; i += stride) {
    float4 v = s4[i];
    uint2 o;
    o.x = (u32)f2bf(v.x) | ((u32)f2bf(v.y) << 16);
    o.y = (u32)f2bf(v.z) | ((u32)f2bf(v.w) << 16);
    d4[i] = o;
  }
}

// ---------- GEMM1 fused: hidden = silu(x@Wg^T) * (x@Wu^T) ----------
// Tile: 128 rows x 128 hidden cols, BK=64, ring-3 LDS, counted vmcnt.
// 8 waves: wr=w>>2 (2 row groups of 64), wc=w&3 (4 col groups of 32).

__global__ __launch_bounds__(512) void gemm1_silu(const u16* __restrict__ Xb,
                                                  const u16* __restrict__ Wgu,
                                                  u16* __restrict__ Hid,
                                                  long sX, long sW, long sH) {
  const int z = blockIdx.z;
  Xb += (long)z * sX;
  Wgu += (long)z * sW;
  Hid += (long)z * sH;

  const int bx = blockIdx.x;  // hidden-col tile (128)
  const int by = blockIdx.y;  // row tile (128)
  const int tid = threadIdx.x;
  const int w = tid >> 6;
  const int lane = tid & 63;
  const int wr = w >> 2, wc = w & 3;

  // per-buf: A[128][64] (8192) + Bg[128][64] (8192) + Bu[128][64] (8192)
  __shared__ __attribute__((aligned(16))) u16 lds[3 * 24576];

  // staging: row within 64-row slab = w*8 + lane>>3; swizzled src granule
  const int srow = (w << 3) + (lane >> 3);
  const int scol = (((lane & 7) ^ (lane >> 3)) << 3);
  const u16* gA = Xb + (size_t)((by << 7) + srow) * H_ + scol;
  const u16* gBg = Wgu + (size_t)((bx << 7) + srow) * H_ + scol;
  const u16* gBu = gBg + (size_t)F_ * H_;

  auto stage = [&](int t, int buf) {
    u16* L = &lds[buf * 24576];
    const int ko = t << 6;
    const int wb = w << 3;
#pragma unroll
    for (int i = 0; i < 2; ++i) {
      gload16(gA + (size_t)(i * 64) * H_ + ko, &L[((i << 6) + wb) << 6]);
      gload16(gBg + (size_t)(i * 64) * H_ + ko,
              &L[8192 + (((i << 6) + wb) << 6)]);
      gload16(gBu + (size_t)(i * 64) * H_ + ko,
              &L[16384 + (((i << 6) + wb) << 6)]);
    }
  };

  f32x4 accG[4][2] = {};
  f32x4 accU[4][2] = {};
  const int fr = lane & 15, q = lane >> 4, l7 = lane & 7;

  auto comp = [&](int buf) {
    const u16* L = &lds[buf * 24576];
    bf16x8 a[4][2], bg[2][2], bu[2][2];
#pragma unroll
    for (int ni = 0; ni < 2; ++ni)
#pragma unroll
      for (int ks = 0; ks < 2; ++ks) {
        int r = (wc << 5) + (ni << 4) + fr;
        int off = (r << 6) + ((((ks << 2) + q) ^ l7) << 3);
        bg[ni][ks] = *(const bf16x8*)&L[8192 + off];
        bu[ni][ks] = *(const bf16x8*)&L[16384 + off];
      }
#pragma unroll
    for (int mi = 0; mi < 4; ++mi)
#pragma unroll
      for (int ks = 0; ks < 2; ++ks) {
        int r = (wr << 6) + (mi << 4) + fr;
        a[mi][ks] = *(const bf16x8*)&L[(r << 6) + ((((ks << 2) + q) ^ l7) << 3)];
      }
    __builtin_amdgcn_s_setprio(1);
#pragma unroll
    for (int mi = 0; mi < 4; ++mi)
#pragma unroll
      for (int ni = 0; ni < 2; ++ni)
#pragma unroll
        for (int ks = 0; ks < 2; ++ks) {
          mfma_b(accG[mi][ni], a[mi][ks], bg[ni][ks]);
          mfma_b(accU[mi][ni], a[mi][ks], bu[ni][ks]);
        }
    __builtin_amdgcn_s_setprio(0);
  };

  const int NT = H_ / 64;  // 32
  stage(0, 0);
  stage(1, 1);
  int b0 = 0, b1 = 1, b2 = 2;
  for (int t = 0; t < NT - 2; ++t) {
    stage(t + 2, b2);
    WAITV(12);
    BAR;
    FENCE;
    comp(b0);
    FENCE;
    BAR;
    int tmp = b0; b0 = b1; b1 = b2; b2 = tmp;
  }
  WAITV(6); BAR; FENCE;
  comp(b0);
  FENCE; BAR;
  WAITV(0); BAR; FENCE;
  comp(b1);

  // epilogue: silu(g)*u -> bf16
  const int row0 = (by << 7) + (wr << 6) + (q << 2);
  const int col0 = (bx << 7) + (wc << 5) + fr;
#pragma unroll
  for (int mi = 0; mi < 4; ++mi)
#pragma unroll
    for (int ni = 0; ni < 2; ++ni)
#pragma unroll
      for (int j = 0; j < 4; ++j) {
        float g = accG[mi][ni][j];
        float u = accU[mi][ni][j];
        float h = (g / (1.f + __expf(-g))) * u;
        Hid[(size_t)(row0 + (mi << 4) + j) * F_ + col0 + (ni << 4)] = f2bf(h);
      }
}

// ---------- GEMM2: out = hidden @ w_down^T (fp32 out) ----------
// Tile: 256 rows x 128 cols, BK=64, ring-3 LDS, counted vmcnt.
// 8 waves: wr=w>>1 (4 row groups of 64), wc=w&1 (2 col groups of 64).

__global__ __launch_bounds__(512) void gemm2_down(const u16* __restrict__ Hd,
                                                  const u16* __restrict__ Wd,
                                                  float* __restrict__ Out,
                                                  long sH, long sW, long sO) {
  const int z = blockIdx.z;
  Hd += (long)z * sH;
  Wd += (long)z * sW;
  Out += (long)z * sO;

  const int bx = blockIdx.x;  // H-col tile (128)
  const int by = blockIdx.y;  // row tile (256)
  const int tid = threadIdx.x;
  const int w = tid >> 6;
  const int lane = tid & 63;
  const int wr = w >> 1, wc = w & 1;

  // per-buf: A[256][64] (16384) + B[128][64] (8192)
  __shared__ __attribute__((aligned(16))) u16 lds[3 * 24576];

  const int srow = (w << 3) + (lane >> 3);
  const int scol = (((lane & 7) ^ (lane >> 3)) << 3);
  const u16* gA = Hd + (size_t)((by << 8) + srow) * F_ + scol;
  const u16* gB = Wd + (size_t)((bx << 7) + srow) * F_ + scol;

  auto stage = [&](int t, int buf) {
    u16* L = &lds[buf * 24576];
    const int ko = t << 6;
    const int wb = w << 3;
#pragma unroll
    for (int i = 0; i < 4; ++i)
      gload16(gA + (size_t)(i * 64) * F_ + ko, &L[((i << 6) + wb) << 6]);
#pragma unroll
    for (int i = 0; i < 2; ++i)
      gload16(gB + (size_t)(i * 64) * F_ + ko,
              &L[16384 + (((i << 6) + wb) << 6)]);
  };

  f32x4 acc[4][4] = {};
  const int fr = lane & 15, q = lane >> 4, l7 = lane & 7;

  auto comp = [&](int buf) {
    const u16* L = &lds[buf * 24576];
    bf16x8 a[4][2], b[4][2];
#pragma unroll
    for (int ni = 0; ni < 4; ++ni)
#pragma unroll
      for (int ks = 0; ks < 2; ++ks) {
        int r = (wc << 6) + (ni << 4) + fr;
        b[ni][ks] =
            *(const bf16x8*)&L[16384 + (r << 6) + ((((ks << 2) + q) ^ l7) << 3)];
      }
#pragma unroll
    for (int mi = 0; mi < 4; ++mi)
#pragma unroll
      for (int ks = 0; ks < 2; ++ks) {
        int r = (wr << 6) + (mi << 4) + fr;
        a[mi][ks] = *(const bf16x8*)&L[(r << 6) + ((((ks << 2) + q) ^ l7) << 3)];
      }
    __builtin_amdgcn_s_setprio(1);
#pragma unroll
    for (int mi = 0; mi < 4; ++mi)
#pragma unroll
      for (int ni = 0; ni < 4; ++ni)
#pragma unroll
        for (int ks = 0; ks < 2; ++ks)
          mfma_b(acc[mi][ni], a[mi][ks], b[ni][ks]);
    __builtin_amdgcn_s_setprio(0);
  };

  const int NT = F_ / 64;  // 64
  stage(0, 0);
  stage(1, 1);
  int b0 = 0, b1 = 1, b2 = 2;
  for (int t = 0; t < NT - 2; ++t) {
    stage(t + 2, b2);
    WAITV(12);
    BAR;
    FENCE;
    comp(b0);
    FENCE;
    BAR;
    int tmp = b0; b0 = b1; b1 = b2; b2 = tmp;
  }
  WAITV(6); BAR; FENCE;
  comp(b0);
  FENCE; BAR;
  WAITV(0); BAR; FENCE;
  comp(b1);

  const int row0 = (by << 8) + (wr << 6) + (q << 2);
  const int col0 = (bx << 7) + (wc << 6) + fr;
#pragma unroll
  for (int mi = 0; mi < 4; ++mi)
#pragma unroll
    for (int ni = 0; ni < 4; ++ni)
#pragma unroll
      for (int j = 0; j < 4; ++j)
        Out[(size_t)(row0 + (mi << 4) + j) * H_ + col0 + (ni << 4)] =
            acc[mi][ni][j];
}

// ---------- host ----------

extern "C" void kernel_launch(void* const* d_in, const int* in_sizes, int n_in,
                              void* d_out, int out_size, void* d_ws,
                              size_t ws_size, hipStream_t stream) {
  (void)in_sizes;
  (void)n_in;
  (void)out_size;
  const float* x = (const float*)d_in[0];
  const float* wgu = (const float*)d_in[1];
  const float* wdn = (const float*)d_in[2];
  float* out = (float*)d_out;
  u16* ws = (u16*)d_ws;

  const size_t xbN = (size_t)T_ * H_;
  const size_t wguN = (size_t)E_ * 2 * F_ * H_;
  const size_t wdnN = (size_t)E_ * H_ * F_;
  const size_t hidN = (size_t)T_ * F_;
  const size_t fullBytes = (xbN + wguN + wdnN + hidN) * 2;  // 576 MiB

  dim3 cblk(256), gblk(512);

  if (ws_size >= fullBytes) {
    u16* xb = ws;
    u16* wgub = xb + xbN;
    u16* wdnb = wgub + wguN;
    u16* hid = wdnb + wdnN;
    cvt_kernel<<<2048, cblk, 0, stream>>>(x, xb, (long)(xbN / 4));
    cvt_kernel<<<4096, cblk, 0, stream>>>(wgu, wgub, (long)(wguN / 4));
    cvt_kernel<<<4096, cblk, 0, stream>>>(wdn, wdnb, (long)(wdnN / 4));
    gemm1_silu<<<dim3(F_ / 128, TE_ / 128, E_), gblk, 0, stream>>>(
        xb, wgub, hid, (long)TE_ * H_, (long)2 * F_ * H_, (long)TE_ * F_);
    gemm2_down<<<dim3(H_ / 128, TE_ / 256, E_), gblk, 0, stream>>>(
        hid, wdnb, out, (long)TE_ * F_, (long)H_ * F_, (long)TE_ * H_);
  } else {
    u16* xb = ws;
    u16* wgub = xb + (size_t)TE_ * H_;
    u16* wdnb = wgub + (size_t)2 * F_ * H_;
    u16* hid = wdnb + (size_t)H_ * F_;
    for (int e = 0; e < E_; ++e) {
      cvt_kernel<<<1024, cblk, 0, stream>>>(x + (size_t)e * TE_ * H_, xb,
                                            (long)((size_t)TE_ * H_ / 4));
      cvt_kernel<<<2048, cblk, 0, stream>>>(wgu + (size_t)e * 2 * F_ * H_, wgub,
                                            (long)((size_t)2 * F_ * H_ / 4));
      cvt_kernel<<<2048, cblk, 0, stream>>>(wdn + (size_t)e * H_ * F_, wdnb,
                                            (long)((size_t)H_ * F_ / 4));
      gemm1_silu<<<dim3(F_ / 128, TE_ / 128, 1), gblk, 0, stream>>>(xb, wgub,
                                                                    hid, 0, 0,
                                                                    0);
      gemm2_down<<<dim3(H_ / 128, TE_ / 256, 1), gblk, 0, stream>>>(
          hid, wdnb, out + (size_t)e * TE_ * H_, 0, 0, 0);
    }
  }
}